// Round 3
// baseline (69.799 us; speedup 1.0000x reference)
//
#include <hip/hip_runtime.h>
#include <math.h>

// SSIM 1D loss: B=16, C=32, T=48000, window=11, sigma=1.5, zero padding.
// u/v reformulation: u=p+t, v=p-t =>
//   conv(u)=s1+s2, conv(v)=s1-s2, conv(u^2)=s11+2*s12+s22, conv(v^2)=s11-2*s12+s22
// => 4 depthwise convs, 2 squares/elem.
// R3 fix vs R2: window is pulled from LDS ONCE per thread via 5 aligned
// ds_read_b128 per array (R2 compiled to per-tap ds_read_b32 -> LDS-issue-bound).
constexpr int T     = 48000;
constexpr int TPB   = 256;
constexpr int OPT   = 4;               // outputs/thread; 4 => 16B-aligned window quads
constexpr int TILE  = TPB * OPT;       // 1024
constexpr int TPR   = (T + TILE - 1) / TILE;  // 47 (tail tile: 896 valid)
constexpr int HALO  = 8;               // need 5; 8 keeps float4 alignment
constexpr int SSPAN = TILE + 2 * HALO; // 1040
constexpr int NF4   = SSPAN / 4;       // 260
constexpr float C1f = 0.0001f;         // 0.01^2
constexpr float C2f = 0.0009f;         // 0.03^2

struct W11 { float w[11]; };

__global__ __launch_bounds__(TPB, 4) void ssim_main(
    const float* __restrict__ pred, const float* __restrict__ targ,
    float* __restrict__ partial, W11 wts)
{
    __shared__ __align__(16) float su[SSPAN];
    __shared__ __align__(16) float sv[SSPAN];
    __shared__ float wsum[TPB / 64];

    const int row  = blockIdx.x / TPR;
    const int tile = blockIdx.x % TPR;
    const int ts   = tile * TILE;
    const float* pr = pred + (size_t)row * T;
    const float* tr = targ + (size_t)row * T;

    // ---- stage u,v tile + halo to LDS (zero-fill OOB == lax zero padding) ----
    {
        const int k = threadIdx.x;
        #pragma unroll
        for (int pass = 0; pass < 2; pass++) {
            const int kk = k + pass * TPB;
            if (pass == 0 || kk < NF4) {
                const int g4 = ts - HALO + 4 * kk;       // multiple of 4 -> 16B aligned
                float4 a = {0.f,0.f,0.f,0.f}, b = {0.f,0.f,0.f,0.f};
                if (g4 >= 0 && g4 <= T - 4) {            // whole quad in-bounds (T%4==0)
                    a = *reinterpret_cast<const float4*>(pr + g4);
                    b = *reinterpret_cast<const float4*>(tr + g4);
                }
                float4 u, v;
                u.x = a.x + b.x; u.y = a.y + b.y; u.z = a.z + b.z; u.w = a.w + b.w;
                v.x = a.x - b.x; v.y = a.y - b.y; v.z = a.z - b.z; v.w = a.w - b.w;
                *reinterpret_cast<float4*>(su + 4 * kk) = u;
                *reinterpret_cast<float4*>(sv + 4 * kk) = v;
            }
        }
    }
    __syncthreads();

    // ---- window -> registers, ONCE: staged[4t .. 4t+19] via 5 b128 per array ----
    // output m (m=0..3) = tile-rel 4t+m, needs staged[4t+3+m .. 4t+13+m]
    const int tq = 4 * threadIdx.x;
    const float4* su4 = reinterpret_cast<const float4*>(su + tq);
    const float4* sv4 = reinterpret_cast<const float4*>(sv + tq);
    const float4 ua = su4[0], ub = su4[1], uc = su4[2], ud = su4[3], ue = su4[4];
    const float4 va = sv4[0], vb = sv4[1], vc = sv4[2], vd = sv4[3], ve = sv4[4];

    float U[20] = {ua.x,ua.y,ua.z,ua.w, ub.x,ub.y,ub.z,ub.w, uc.x,uc.y,uc.z,uc.w,
                   ud.x,ud.y,ud.z,ud.w, ue.x,ue.y,ue.z,ue.w};
    float V[20] = {va.x,va.y,va.z,va.w, vb.x,vb.y,vb.z,vb.w, vc.x,vc.y,vc.z,vc.w,
                   vd.x,vd.y,vd.z,vd.w, ve.x,ve.y,ve.z,ve.w};
    float UU[20], VV[20];                        // only [3..16] used
    #pragma unroll
    for (int i = 3; i <= 16; i++) { UU[i] = U[i] * U[i]; VV[i] = V[i] * V[i]; }

    float ca[OPT] = {}, cb[OPT] = {}, cc[OPT] = {}, cd[OPT] = {};
    #pragma unroll
    for (int k = 0; k < 11; k++) {
        const float wk = wts.w[k];               // SGPR-resident
        #pragma unroll
        for (int m = 0; m < OPT; m++) {
            ca[m] = fmaf(wk, U[3 + m + k],  ca[m]);   // s1+s2
            cb[m] = fmaf(wk, V[3 + m + k],  cb[m]);   // s1-s2
            cc[m] = fmaf(wk, UU[3 + m + k], cc[m]);   // s11+2s12+s22
            cd[m] = fmaf(wk, VV[3 + m + k], cd[m]);   // s11-2s12+s22
        }
    }

    // ---- SSIM epilogue: loss = (#valid) - sum(ssim) ----
    float acc = 0.f;
    float valid = 0.f;
    const bool full = (ts + TILE <= T);          // block-uniform
    #pragma unroll
    for (int m = 0; m < OPT; m++) {
        const float aa = ca[m] * ca[m], bb = cb[m] * cb[m];
        const float e  = 0.5f * (aa - bb);       // 2*mu1*mu2
        const float f  = 0.5f * (aa + bb);       // mu1^2 + mu2^2
        const float t2 = 0.5f * (cc[m] - cd[m]); // 2*sigma12 + 2*mu12
        const float sP = 0.5f * (cc[m] + cd[m]); // sig1+sig2 + mu1^2+mu2^2
        const float num = (e + C1f) * (t2 - e + C2f);
        const float den = (f + C1f) * (sP - f + C2f);
        const float q   = num * __builtin_amdgcn_rcpf(den);   // den >= C1*C2 > 0
        if (full) { acc += q; valid += 1.f; }
        else {
            const bool ok = (ts + tq + m) < T;
            acc   += ok ? q : 0.f;
            valid += ok ? 1.f : 0.f;
        }
    }
    float loss = valid - acc;

    // ---- block reduction -> one partial per block ----
    #pragma unroll
    for (int off = 32; off; off >>= 1) loss += __shfl_down(loss, off);
    if ((threadIdx.x & 63) == 0) wsum[threadIdx.x >> 6] = loss;
    __syncthreads();
    if (threadIdx.x == 0) {
        float s = 0.f;
        #pragma unroll
        for (int i = 0; i < TPB / 64; i++) s += wsum[i];
        partial[blockIdx.x] = s;
    }
}

__global__ __launch_bounds__(256) void ssim_reduce(
    const float4* __restrict__ partial4, int n4, float* __restrict__ out, float inv_n)
{
    float s = 0.f;
    for (int i = threadIdx.x; i < n4; i += 256) {
        const float4 p = partial4[i];
        s += (p.x + p.y) + (p.z + p.w);
    }
    #pragma unroll
    for (int off = 32; off; off >>= 1) s += __shfl_down(s, off);
    __shared__ float ws[4];
    if ((threadIdx.x & 63) == 0) ws[threadIdx.x >> 6] = s;
    __syncthreads();
    if (threadIdx.x == 0) {
        float t = 0.f;
        #pragma unroll
        for (int i = 0; i < 4; i++) t += ws[i];
        out[0] = t * inv_n;
    }
}

extern "C" void kernel_launch(void* const* d_in, const int* in_sizes, int n_in,
                              void* d_out, int out_size, void* d_ws, size_t ws_size,
                              hipStream_t stream)
{
    const float* pred = (const float*)d_in[0];
    const float* targ = (const float*)d_in[1];
    float* out = (float*)d_out;
    float* partial = (float*)d_ws;

    const int n      = in_sizes[0];     // B*C*T = 24,576,000
    const int rows   = n / T;           // 512
    const int blocks = rows * TPR;      // 24,064 (needs ~94 KB of d_ws)

    // Gaussian window computed on host in double (matches numpy), cast to f32.
    W11 wts;
    double g[11], s = 0.0;
    for (int i = 0; i < 11; i++) { g[i] = exp(-((i - 5) * (i - 5)) / 4.5); s += g[i]; }
    for (int i = 0; i < 11; i++) wts.w[i] = (float)(g[i] / s);

    hipLaunchKernelGGL(ssim_main, dim3(blocks), dim3(TPB), 0, stream,
                       pred, targ, partial, wts);
    hipLaunchKernelGGL(ssim_reduce, dim3(1), dim3(256), 0, stream,
                       (const float4*)partial, blocks / 4, out, 1.0f / (float)n);
}

// Round 4
// 63.251 us; speedup vs baseline: 1.1035x; 1.1035x over previous
//
#include <hip/hip_runtime.h>
#include <math.h>

// SSIM 1D loss: B=16, C=32, T=48000, window=11, sigma=1.5, zero padding.
// u/v reformulation: u=p+t, v=p-t =>
//   conv(u)=mu1+mu2, conv(v)=mu1-mu2, conv(u^2)=s11+2s12+s22, conv(v^2)=s11-2s12+s22
// => 4 depthwise convs, 2 squares/elem.
//
// R4: NO LDS. R1-R3 all plateaued at ~70-75us with VGPR=32..40 because hipcc
// rematerializes LDS reads into the conv loop (per-tap ds_read) instead of
// keeping the window in registers -> LDS-issue-bound. Here each thread loads
// its own window directly from global (5x float4 per input, L1 absorbs the
// overlap) and an empty inline-asm "+v" barrier pins the values in VGPRs so
// the backend cannot re-read them.
constexpr int T     = 48000;
constexpr int TPB   = 256;
constexpr int OPT   = 4;            // outputs per thread
constexpr int TPROW = T / OPT;      // 12000 threads per row (exact)
constexpr float C1f = 0.0001f;      // 0.01^2
constexpr float C2f = 0.0009f;      // 0.03^2

struct W11 { float w[11]; };

#define KEEP4(v) asm("" : "+v"((v).x), "+v"((v).y), "+v"((v).z), "+v"((v).w))

__global__ __launch_bounds__(TPB, 3) void ssim_main(
    const float* __restrict__ pred, const float* __restrict__ targ,
    float* __restrict__ partial, int nthreads, W11 wts)
{
    const int tid  = blockIdx.x * TPB + (int)threadIdx.x;
    const bool live = tid < nthreads;
    const int t0   = live ? tid : 0;
    const int row  = t0 / TPROW;                 // magic-mul
    const int pos  = (t0 - row * TPROW) * OPT;   // first output index in row
    const float* pr = pred + (size_t)row * T;
    const float* tr = targ + (size_t)row * T;
    const int g0 = pos - 8;                      // first loaded element, 16B aligned

    // ---- window loads: elements [pos-8 .. pos+11]; taps use [pos-5 .. pos+8] ----
    float4 pq[5], tq[5];
    if (pos >= 8 && pos + 12 <= T) {             // interior: unguarded
        const float4* P4 = reinterpret_cast<const float4*>(pr + g0);
        const float4* Q4 = reinterpret_cast<const float4*>(tr + g0);
        #pragma unroll
        for (int j = 0; j < 5; j++) { pq[j] = P4[j]; tq[j] = Q4[j]; }
    } else {                                     // 4 threads per row: zero-fill OOB quads
        #pragma unroll
        for (int j = 0; j < 5; j++) {
            const int q = g0 + 4 * j;            // quad fully in or fully out (T%4==0)
            float4 a = {0.f,0.f,0.f,0.f}, b = {0.f,0.f,0.f,0.f};
            if (q >= 0 && q + 4 <= T) {
                a = *reinterpret_cast<const float4*>(pr + q);
                b = *reinterpret_cast<const float4*>(tr + q);
            }
            pq[j] = a; tq[j] = b;
        }
    }
    #pragma unroll
    for (int j = 0; j < 5; j++) { KEEP4(pq[j]); KEEP4(tq[j]); }

    const float P[20] = {pq[0].x,pq[0].y,pq[0].z,pq[0].w, pq[1].x,pq[1].y,pq[1].z,pq[1].w,
                         pq[2].x,pq[2].y,pq[2].z,pq[2].w, pq[3].x,pq[3].y,pq[3].z,pq[3].w,
                         pq[4].x,pq[4].y,pq[4].z,pq[4].w};
    const float Q[20] = {tq[0].x,tq[0].y,tq[0].z,tq[0].w, tq[1].x,tq[1].y,tq[1].z,tq[1].w,
                         tq[2].x,tq[2].y,tq[2].z,tq[2].w, tq[3].x,tq[3].y,tq[3].z,tq[3].w,
                         tq[4].x,tq[4].y,tq[4].z,tq[4].w};

    // only indices 3..16 feed the taps
    float U[17], V[17], UU[17], VV[17];
    #pragma unroll
    for (int i = 3; i <= 16; i++) {
        U[i] = P[i] + Q[i];
        V[i] = P[i] - Q[i];
        UU[i] = U[i] * U[i];
        VV[i] = V[i] * V[i];
    }

    float ca[OPT] = {}, cb[OPT] = {}, cc[OPT] = {}, cd[OPT] = {};
    #pragma unroll
    for (int k = 0; k < 11; k++) {
        const float wk = wts.w[k];               // SGPR-resident
        #pragma unroll
        for (int m = 0; m < OPT; m++) {
            ca[m] = fmaf(wk, U[3 + m + k],  ca[m]);
            cb[m] = fmaf(wk, V[3 + m + k],  cb[m]);
            cc[m] = fmaf(wk, UU[3 + m + k], cc[m]);
            cd[m] = fmaf(wk, VV[3 + m + k], cd[m]);
        }
    }

    // ---- SSIM epilogue; all OPT outputs are in-bounds by construction ----
    float qsum = 0.f;
    #pragma unroll
    for (int m = 0; m < OPT; m++) {
        const float aa = ca[m] * ca[m], bb = cb[m] * cb[m];
        const float e  = 0.5f * (aa - bb);        // 2*mu1*mu2
        const float f  = 0.5f * (aa + bb);        // mu1^2+mu2^2
        const float t2 = 0.5f * (cc[m] - cd[m]);  // 2*s12
        const float sP = 0.5f * (cc[m] + cd[m]);  // s11+s22
        const float num = (e + C1f) * (t2 - e + C2f);
        const float den = (f + C1f) * (sP - f + C2f);
        qsum += num * __builtin_amdgcn_rcpf(den); // den >= C1*C2 > 0
    }
    qsum = live ? qsum : 0.f;

    // ---- block reduction -> one partial per block ----
    #pragma unroll
    for (int off = 32; off; off >>= 1) qsum += __shfl_down(qsum, off);
    __shared__ float wsum[TPB / 64];
    if ((threadIdx.x & 63) == 0) wsum[threadIdx.x >> 6] = qsum;
    __syncthreads();
    if (threadIdx.x == 0) {
        float s = 0.f;
        #pragma unroll
        for (int i = 0; i < TPB / 64; i++) s += wsum[i];
        partial[blockIdx.x] = s;
    }
}

__global__ __launch_bounds__(256) void ssim_reduce(
    const float4* __restrict__ partial4, int n4, float* __restrict__ out, float inv_n)
{
    float s = 0.f;
    for (int i = threadIdx.x; i < n4; i += 256) {
        const float4 p = partial4[i];
        s += (p.x + p.y) + (p.z + p.w);
    }
    #pragma unroll
    for (int off = 32; off; off >>= 1) s += __shfl_down(s, off);
    __shared__ float ws[4];
    if ((threadIdx.x & 63) == 0) ws[threadIdx.x >> 6] = s;
    __syncthreads();
    if (threadIdx.x == 0) {
        float t = 0.f;
        #pragma unroll
        for (int i = 0; i < 4; i++) t += ws[i];
        out[0] = 1.f - t * inv_n;                // mean(1-ssim) = 1 - mean(ssim)
    }
}

extern "C" void kernel_launch(void* const* d_in, const int* in_sizes, int n_in,
                              void* d_out, int out_size, void* d_ws, size_t ws_size,
                              hipStream_t stream)
{
    const float* pred = (const float*)d_in[0];
    const float* targ = (const float*)d_in[1];
    float* out = (float*)d_out;
    float* partial = (float*)d_ws;

    const int n        = in_sizes[0];            // B*C*T = 24,576,000
    const int rows     = n / T;                  // 512
    const int nthreads = rows * TPROW;           // 6,144,000
    const int blocks   = (nthreads + TPB - 1) / TPB;  // 24,000 (96 KB of d_ws)

    // Gaussian window computed on host in double (matches numpy), cast to f32.
    W11 wts;
    double g[11], s = 0.0;
    for (int i = 0; i < 11; i++) { g[i] = exp(-((i - 5) * (i - 5)) / 4.5); s += g[i]; }
    for (int i = 0; i < 11; i++) wts.w[i] = (float)(g[i] / s);

    hipLaunchKernelGGL(ssim_main, dim3(blocks), dim3(TPB), 0, stream,
                       pred, targ, partial, nthreads, wts);
    hipLaunchKernelGGL(ssim_reduce, dim3(1), dim3(256), 0, stream,
                       (const float4*)partial, blocks / 4, out, 1.0f / (float)n);
}